// Round 4
// baseline (309.371 us; speedup 1.0000x reference)
//
#include <hip/hip_runtime.h>
#include <hip/hip_bf16.h>

// Problem constants
#define B_      16
#define Q_      300
#define BQ      (B_*Q_)        // 4800
#define HIDDEN_ 256
#define NHEADS  8
#define PTOT    16             // points per head (4 levels x 4)
#define S_      13294
#define NOFF    256            // total_points*2
#define NATTN   128            // total_points
#define NCOLS   (NOFF+NATTN)   // 384 fused output columns
#define OSTRIDE 388            // o_s row stride
#define AS      264            // A_s row stride in bf16
#define MQ      8              // queries per fused block
#define TS      68             // tap-table stride (col*68+j -> conflict-free reads)

typedef __attribute__((ext_vector_type(8))) short bf16x8;   // 8 bf16 (4 VGPRs)
typedef __attribute__((ext_vector_type(4))) float floatx4;  // MFMA C/D

// round-to-nearest-even f32 -> bf16 bits
__device__ __forceinline__ short f2bf(float f) {
    unsigned u = __float_as_uint(f);
    unsigned r = (u + 0x7fffu + ((u >> 16) & 1u)) >> 16;
    return (short)r;
}

// ---------------------------------------------------------------------------
// Kernel 0: build W^T in bf16:  Wt[j][k] = W[:,j][k]   (384 x 256, k-contig)
// ---------------------------------------------------------------------------
__global__ __launch_bounds__(256) void prep_kernel(
    const float* __restrict__ W_off,   // (256,256)
    const float* __restrict__ W_attn,  // (256,128)
    short* __restrict__ Wt)            // (384,256) bf16
{
    int id = blockIdx.x * 256 + threadIdx.x;   // 0 .. 98303
    int j = id >> 8;
    int k = id & 255;
    float v = (j < NOFF) ? W_off[k * NOFF + j] : W_attn[k * NATTN + (j - NOFF)];
    Wt[id] = f2bf(v);
}

// ---------------------------------------------------------------------------
// Fused kernel: MFMA projection (8 real rows in a 16-row tile) -> softmax +
// tap computation (parallel-redundant, 1024 tasks) -> bilinear gather.
// grid = 600 (8 queries each), block = 512.
// Tap tables row_s/w_s: [col][j] with stride 68 -> phase-C reads hit 8
// distinct banks per wave (broadcast x8 within a head) = conflict-free.
// ---------------------------------------------------------------------------
__global__ __launch_bounds__(512) void fused_kernel(
    const float* __restrict__ hidden,   // (4800, 256) f32
    const float* __restrict__ refp,     // (4800, 4)
    const short* __restrict__ Wt,       // (384, 256) bf16, k-contiguous
    const float* __restrict__ b_off,    // (256)
    const float* __restrict__ b_attn,   // (128)
    const float* __restrict__ enc,      // (16, 13294, 256)
    float* __restrict__ out,            // (4800, 256)
    float* __restrict__ aw_out)         // (4800, 128)
{
    __shared__ float o_s[MQ * OSTRIDE];        // 12.4 KB logits (8 rows)
    __shared__ int   row_s[MQ * NHEADS * TS];  // 17.4 KB tap rows   (A_s unioned)
    __shared__ float w_s[MQ * NHEADS * TS];    // 17.4 KB tap weights

    short* A_s = (short*)row_s;                // 16 x 264 bf16 = 8.25 KB, phase A only

    const int tid  = threadIdx.x;
    const int row0 = blockIdx.x * MQ;

    // ---- Phase A: stage A (8 real rows + 8 zero rows), MFMA GEMM ----
    {
        const int r  = tid >> 5;               // 0..15
        const int ks = (tid & 31) * 8;
        bf16x8 v;
        if (r < MQ) {
            const float* hp = hidden + (size_t)(row0 + r) * HIDDEN_ + ks;
            float4 a0 = *(const float4*)hp;
            float4 a1 = *(const float4*)(hp + 4);
            v[0] = f2bf(a0.x); v[1] = f2bf(a0.y); v[2] = f2bf(a0.z); v[3] = f2bf(a0.w);
            v[4] = f2bf(a1.x); v[5] = f2bf(a1.y); v[6] = f2bf(a1.z); v[7] = f2bf(a1.w);
        } else {
            v = (bf16x8)0;
        }
        *(bf16x8*)(A_s + r * AS + ks) = v;
    }
    __syncthreads();

    {
        const int wave = tid >> 6;             // 0..7
        const int lane = tid & 63;
        const int m    = lane & 15;
        const int quad = lane >> 4;

        floatx4 acc[3];
        #pragma unroll
        for (int i = 0; i < 3; ++i)
            #pragma unroll
            for (int r = 0; r < 4; ++r) acc[i][r] = 0.f;

        #pragma unroll
        for (int k0 = 0; k0 < HIDDEN_; k0 += 32) {
            const int kk = k0 + quad * 8;
            bf16x8 af = *(const bf16x8*)(A_s + m * AS + kk);
            #pragma unroll
            for (int i = 0; i < 3; ++i) {
                const int n0 = (wave * 3 + i) * 16;
                bf16x8 bf = *(const bf16x8*)(Wt + (size_t)(n0 + m) * HIDDEN_ + kk);
                acc[i] = __builtin_amdgcn_mfma_f32_16x16x32_bf16(af, bf, acc[i], 0, 0, 0);
            }
        }
        __syncthreads();   // A_s dead; row_s reuse safe after this

        // D layout: col = lane&15, row = quad*4 + reg; only rows 0..7 real
        if (quad < 2) {
            #pragma unroll
            for (int i = 0; i < 3; ++i) {
                const int col = (wave * 3 + i) * 16 + m;
                const float bias = (col < NOFF) ? b_off[col] : b_attn[col - NOFF];
                #pragma unroll
                for (int r = 0; r < 4; ++r)
                    o_s[(quad * 4 + r) * OSTRIDE + col] = acc[i][r] + bias;
            }
        }
    }
    __syncthreads();

    // ---- Phase B: softmax + location + taps. 1024 tasks, 2 per thread ----
    #pragma unroll
    for (int half = 0; half < 2; ++half) {
        const int t  = tid + half * 512;       // task id
        const int r  = t >> 7;                 // 0..7
        const int hd = (t >> 4) & 7;
        const int p  = t & 15;
        const int row = row0 + r;

        // softmax (redundant within the 16-thread (r,hd) group; LDS broadcast)
        const float* lg = &o_s[r * OSTRIDE + NOFF + hd * PTOT];
        float mx = -1e30f;
        #pragma unroll
        for (int q = 0; q < PTOT; ++q) mx = fmaxf(mx, lg[q]);
        float sum = 0.f;
        #pragma unroll
        for (int q = 0; q < PTOT; ++q) sum += __expf(lg[q] - mx);
        const float awv = __expf(lg[p] - mx) / sum;

        aw_out[(size_t)row * NATTN + hd * PTOT + p] = awv;

        const float4 rp = ((const float4*)refp)[row];
        const float ox = o_s[r * OSTRIDE + (hd * PTOT + p) * 2];
        const float oy = o_s[r * OSTRIDE + (hd * PTOT + p) * 2 + 1];
        const float lx = rp.x + ox * (0.125f * rp.z);   // 0.25 * 0.5 * w
        const float ly = rp.y + oy * (0.125f * rp.w);

        const int lvl   = p >> 2;
        const int Wl    = (lvl == 0) ? 100 : (lvl == 1) ? 50 : (lvl == 2) ? 25 : 13;
        const int start = (lvl == 0) ? 0 : (lvl == 1) ? 10000 : (lvl == 2) ? 12500 : 13125;

        const float x = lx * (float)Wl - 0.5f;
        const float y = ly * (float)Wl - 0.5f;
        const float x0f = floorf(x), y0f = floorf(y);
        const float wx1 = x - x0f, wx0 = 1.f - wx1;
        const float wy1 = y - y0f, wy0 = 1.f - wy1;
        const int x0 = (int)x0f, y0 = (int)y0f;
        const int x1 = x0 + 1,  y1 = y0 + 1;

        const int x0c = x0 < 0 ? 0 : (x0 > Wl-1 ? Wl-1 : x0);
        const int x1c = x1 < 0 ? 0 : (x1 > Wl-1 ? Wl-1 : x1);
        const int y0c = y0 < 0 ? 0 : (y0 > Wl-1 ? Wl-1 : y0);
        const int y1c = y1 < 0 ? 0 : (y1 > Wl-1 ? Wl-1 : y1);
        const bool vx0 = (x0 >= 0) & (x0 <= Wl-1);
        const bool vx1 = (x1 >= 0) & (x1 <= Wl-1);
        const bool vy0 = (y0 >= 0) & (y0 <= Wl-1);
        const bool vy1 = (y1 >= 0) & (y1 <= Wl-1);

        const int col  = r * NHEADS + hd;      // 0..63
        const int base = col * TS + p * 4;
        row_s[base + 0] = start + y0c * Wl + x0c;
        row_s[base + 1] = start + y0c * Wl + x1c;
        row_s[base + 2] = start + y1c * Wl + x0c;
        row_s[base + 3] = start + y1c * Wl + x1c;
        w_s[base + 0] = (vy0 & vx0) ? awv * wy0 * wx0 : 0.f;
        w_s[base + 1] = (vy0 & vx1) ? awv * wy0 * wx1 : 0.f;
        w_s[base + 2] = (vy1 & vx0) ? awv * wy1 * wx0 : 0.f;
        w_s[base + 3] = (vy1 & vx1) ? awv * wy1 * wx1 : 0.f;
    }
    __syncthreads();

    // ---- Phase C: gather + accumulate. 512 threads = 8 q x 64 lanes ----
    {
        const int g    = tid >> 6;             // query within block
        const int lane = tid & 63;
        const int hd   = lane >> 3;
        const int cq   = lane & 7;
        const int bq   = row0 + g;
        const int b    = bq / Q_;              // blocks may straddle batches

        const float4* encb = (const float4*)(enc + (size_t)b * S_ * HIDDEN_);
        const int c4   = hd * 8 + cq;
        const int base = (g * NHEADS + hd) * TS;

        float4 acc = make_float4(0.f, 0.f, 0.f, 0.f);

        #pragma unroll 16
        for (int j = 0; j < PTOT * 4; ++j) {
            const int   row = row_s[base + j];   // broadcast across 8 lanes
            const float w   = w_s[base + j];
            const float4 v  = encb[(size_t)row * 64 + c4];
            acc.x = fmaf(w, v.x, acc.x);
            acc.y = fmaf(w, v.y, acc.y);
            acc.z = fmaf(w, v.z, acc.z);
            acc.w = fmaf(w, v.w, acc.w);
        }

        ((float4*)out)[(size_t)bq * 64 + c4] = acc;
    }
}

extern "C" void kernel_launch(void* const* d_in, const int* in_sizes, int n_in,
                              void* d_out, int out_size, void* d_ws, size_t ws_size,
                              hipStream_t stream) {
    const float* hidden = (const float*)d_in[0];   // (16,300,256)
    const float* enc    = (const float*)d_in[1];   // (16,13294,256)
    const float* refp   = (const float*)d_in[2];   // (16,300,1,4)
    const float* W_off  = (const float*)d_in[3];   // (256,256)
    const float* b_off  = (const float*)d_in[4];   // (256)
    const float* W_attn = (const float*)d_in[5];   // (256,128)
    const float* b_attn = (const float*)d_in[6];   // (128)

    float* out    = (float*)d_out;                 // (4800,256)
    float* aw_out = out + (size_t)BQ * HIDDEN_;    // (4800,128)

    short* Wt = (short*)d_ws;                      // 384x256 bf16 = 192 KB

    prep_kernel<<<NCOLS * HIDDEN_ / 256, 256, 0, stream>>>(W_off, W_attn, Wt);
    fused_kernel<<<BQ / MQ, 512, 0, stream>>>(hidden, refp, Wt, b_off, b_attn,
                                              enc, out, aw_out);
}